// Round 4
// baseline (136.187 us; speedup 1.0000x reference)
//
#include <hip/hip_runtime.h>

// PhysicsGuidedAttention: B=2, N=2048, D=768, H=12, Hd=64
// qkv = x @ w_qkv.T ; flash-attn with elevation bias ; out = attn_out @ w_proj.T + b_proj
// R4: attn = KV-parity-split waves (768 even blocks, 12 waves/CU), K via
//     global_load_lds with pre-swizzled global source (dbuf), V reg-transpose
//     written post-barrier (T14). GEMMs = 2-phase dbuf pipeline.

typedef __attribute__((ext_vector_type(8))) short bf16x8;   // 8 bf16 = 4 VGPRs
typedef __attribute__((ext_vector_type(4))) float f32x4;
typedef __attribute__((ext_vector_type(16))) float f32x16;  // 32x32 accumulator

__device__ __forceinline__ unsigned short f2bf(float f) {
  unsigned int u = __builtin_bit_cast(unsigned int, f);
  u += 0x7fffu + ((u >> 16) & 1u);        // round-to-nearest-even
  return (unsigned short)(u >> 16);
}

__device__ __forceinline__ unsigned cvtpk(float lo, float hi) {
  unsigned r;
  asm("v_cvt_pk_bf16_f32 %0, %1, %2" : "=v"(r) : "v"(lo), "v"(hi));
  return r;
}

__device__ __forceinline__ float exp2v(float x) {
  float r;
  asm("v_exp_f32 %0, %1" : "=v"(r) : "v"(x));
  return r;
}

// XOR swizzle on element index: spreads 128B-stride row slots across banks.
__device__ __forceinline__ int sw8(int row) {
  return ((row ^ (row >> 3)) & 7) << 3;
}

__device__ __forceinline__ void gload16(const unsigned short* g, unsigned short* l) {
  __builtin_amdgcn_global_load_lds(
      (const __attribute__((address_space(1))) unsigned int*)g,
      (__attribute__((address_space(3))) unsigned int*)l, 16, 0, 0);
}

// ---------------------------------------------------------------------------
__global__ __launch_bounds__(256)
void cvt_kernel(const float* __restrict__ in, unsigned short* __restrict__ out, int n8) {
  const int i = blockIdx.x * 256 + threadIdx.x;
  if (i >= n8) return;
  const float4 f0 = ((const float4*)in)[i * 2];
  const float4 f1 = ((const float4*)in)[i * 2 + 1];
  uint4 v;
  v.x = (unsigned)f2bf(f0.x) | ((unsigned)f2bf(f0.y) << 16);
  v.y = (unsigned)f2bf(f0.z) | ((unsigned)f2bf(f0.w) << 16);
  v.z = (unsigned)f2bf(f1.x) | ((unsigned)f2bf(f1.y) << 16);
  v.w = (unsigned)f2bf(f1.z) | ((unsigned)f2bf(f1.w) << 16);
  ((uint4*)out)[i] = v;
}

// ---------------------------------------------------------------------------
// C[M,N] = A[M,K] @ B[N,K]^T, bf16, 128x128 tile, BK=32, 2-phase dbuf pipeline.
template<bool OUT_F32>
__global__ __launch_bounds__(256)
void gemm_bt_bf16(const unsigned short* __restrict__ Ap,
                  const unsigned short* __restrict__ Bp,
                  const float* __restrict__ bias, void* __restrict__ Cp,
                  int M, int N, int K) {
  __shared__ __align__(16) unsigned short lds_a[2][128 * 32];
  __shared__ __align__(16) unsigned short lds_b[2][128 * 32];
  const int t = threadIdx.x;
  const int l = t & 63;
  const int w = t >> 6;
  const int wr = w >> 1, wc = w & 1;
  const int brow = blockIdx.x * 128;
  const int bcol = blockIdx.y * 128;
  const int l15 = l & 15, l4 = l >> 4;

  const int srow = t >> 2;
  const int scol = (t & 3) * 8;
  const unsigned short* ga = Ap + (size_t)(brow + srow) * K + scol;
  const unsigned short* gb = Bp + (size_t)(bcol + srow) * K + scol;

  f32x4 acc[4][4] = {};
  const int nk = K >> 5;

  // prologue: stage tile 0 into buf 0
  {
    unsigned short* la = lds_a[0] + w * 512;
    unsigned short* lb = lds_b[0] + w * 512;
    gload16(ga, la);
    gload16(ga + (size_t)64 * K, la + 2048);
    gload16(gb, lb);
    gload16(gb + (size_t)64 * K, lb + 2048);
  }
  __syncthreads();

  int buf = 0;
  for (int kt = 0; kt < nk; ++kt) {
    if (kt + 1 < nk) {                      // issue next stage early (hidden)
      const size_t ko = (size_t)(kt + 1) * 32;
      unsigned short* la = lds_a[buf ^ 1] + w * 512;
      unsigned short* lb = lds_b[buf ^ 1] + w * 512;
      gload16(ga + ko, la);
      gload16(ga + ko + (size_t)64 * K, la + 2048);
      gload16(gb + ko, lb);
      gload16(gb + ko + (size_t)64 * K, lb + 2048);
    }
    bf16x8 af[4], bfr[4];
#pragma unroll
    for (int i = 0; i < 4; ++i) {
      af[i]  = *(const bf16x8*)&lds_a[buf][(wr * 64 + i * 16 + l15) * 32 + l4 * 8];
      bfr[i] = *(const bf16x8*)&lds_b[buf][(wc * 64 + i * 16 + l15) * 32 + l4 * 8];
    }
#pragma unroll
    for (int i = 0; i < 4; ++i)
#pragma unroll
      for (int j = 0; j < 4; ++j)
        acc[i][j] = __builtin_amdgcn_mfma_f32_16x16x32_bf16(af[i], bfr[j], acc[i][j], 0, 0, 0);
    __syncthreads();                        // drains staging vmcnt + read done
    buf ^= 1;
  }

#pragma unroll
  for (int i = 0; i < 4; ++i)
#pragma unroll
    for (int j = 0; j < 4; ++j)
#pragma unroll
      for (int r = 0; r < 4; ++r) {
        const int row = brow + wr * 64 + i * 16 + l4 * 4 + r;
        const int col = bcol + wc * 64 + j * 16 + l15;
        const float v = acc[i][j][r];
        if constexpr (OUT_F32) {
          ((float*)Cp)[(size_t)row * N + col] = v + bias[col];
        } else {
          ((unsigned short*)Cp)[(size_t)row * N + col] = f2bf(v);
        }
      }
}

// ---------------------------------------------------------------------------
// Flash attention, 32x32x16 MFMA, swapped QK^T, no max-tracking.
// grid = (B*H, N/64); 256 thr = 4 waves: wq = w&1 (q sub-tile of 32),
// par = w>>1 (kv parity: wave does tiles 2s+par, s=0..15).
// No-max softmax => parity partials are pure sums; combined via LDS at end.
__global__ __launch_bounds__(256, 3)
void attn_kernel(const unsigned short* __restrict__ qkv,
                 const float* __restrict__ elev,
                 const float* __restrict__ alpha_p,
                 unsigned short* __restrict__ aout) {
  __shared__ __align__(16) unsigned short lds_k[2][2][64 * 64]; // [par][dbuf]
  __shared__ __align__(16) unsigned short lds_vt[2][64 * 64];   // [par][d][kv]
  __shared__ float lds_ej[2][64];
  __shared__ float lds_linv[2][32];

  const int t = threadIdx.x;
  const int l = t & 63;
  const int w = t >> 6;
  const int wq = w & 1;
  const int par = w >> 1;
  const int l31 = l & 31;
  const int h = l >> 5;
  const int b = blockIdx.x / 12, hd = blockIdx.x % 12;
  const int qw = blockIdx.y * 64 + wq * 32;

  const float cE = fmaxf(alpha_p[0], 0.f) * (1.4426950408889634f * 1e-3f);
  const float c1 = 0.18033688011112042f;   // 0.125 * log2(e)

  const size_t rs = 2304;
  const unsigned short* qbase = qkv + ((size_t)b * 2048) * rs + hd * 64;
  const unsigned short* kbase = qbase + 768;
  const unsigned short* vbase = qbase + 1536;

  bf16x8 qa[4];
  {
    const unsigned short* qp = qbase + (size_t)(qw + l31) * rs + h * 8;
#pragma unroll
    for (int ks = 0; ks < 4; ++ks) qa[ks] = *(const bf16x8*)(qp + ks * 16);
  }
  const float eiv = elev[(size_t)b * 2048 + qw + l31] * cE;

  // K gload src swizzle precompute (pre-swizzled global -> linear LDS dest)
  const int lr = l >> 3;          // 0..7
  const int lc = (l & 7) * 8;     // col base

  f32x16 o[2] = {};
  float psum = 0.f;

  const int tp = t & 127;         // index within pair
  const int vr = tp >> 1;         // V row 0..63
  const int vh = (tp & 1) * 32;   // V col half

  uint4 rv[4];
  float evn = 0.f;

  // ---- prologue: stage tile T0 = par ----
  {
    const int kv0 = par * 64;
#pragma unroll
    for (int i = 0; i < 4; ++i) {
      const int ig = wq * 4 + i;
      const int r = ig * 8 + lr;
      const int c = lc ^ (((lr ^ ig) & 7) << 3);
      gload16(kbase + (size_t)(kv0 + r) * rs + c, &lds_k[par][0][ig * 512]);
    }
#pragma unroll
    for (int i = 0; i < 4; ++i)
      rv[i] = *(const uint4*)(vbase + (size_t)(kv0 + vr) * rs + vh + i * 8);
    if (wq == 0) evn = elev[(size_t)b * 2048 + kv0 + l];
#pragma unroll
    for (int i = 0; i < 4; ++i) {
      union { uint4 u; unsigned short s[8]; } vu; vu.u = rv[i];
#pragma unroll
      for (int j = 0; j < 8; ++j) {
        const int d = vh + i * 8 + j;
        lds_vt[par][d * 64 + (vr ^ sw8(d))] = vu.s[j];
      }
    }
    if (wq == 0) lds_ej[par][l] = evn * cE;
  }
  __syncthreads();

  for (int s = 0; s < 16; ++s) {
    const int cb = s & 1;
    const bool more = s < 15;
    if (more) {                    // prefetch tile t+2: K -> kbuf^1, V -> regs
      const int kvn = (2 * (s + 1) + par) * 64;
#pragma unroll
      for (int i = 0; i < 4; ++i) {
        const int ig = wq * 4 + i;
        const int r = ig * 8 + lr;
        const int c = lc ^ (((lr ^ ig) & 7) << 3);
        gload16(kbase + (size_t)(kvn + r) * rs + c, &lds_k[par][cb ^ 1][ig * 512]);
      }
#pragma unroll
      for (int i = 0; i < 4; ++i)
        rv[i] = *(const uint4*)(vbase + (size_t)(kvn + vr) * rs + vh + i * 8);
      if (wq == 0) evn = elev[(size_t)b * 2048 + kvn + l];
    }

    // --- S^T = K x Q ---
    f32x16 st[2] = {};
    __builtin_amdgcn_s_setprio(1);
#pragma unroll
    for (int kst = 0; kst < 4; ++kst) {
      const int col = kst * 16 + h * 8;
#pragma unroll
      for (int mb = 0; mb < 2; ++mb) {
        const int row = mb * 32 + l31;
        bf16x8 kf = *(const bf16x8*)&lds_k[par][cb][row * 64 + (col ^ sw8(row))];
        st[mb] = __builtin_amdgcn_mfma_f32_32x32x16_bf16(kf, qa[kst], st[mb], 0, 0, 0);
      }
    }
    __builtin_amdgcn_s_setprio(0);

    // --- softmax + in-register P pack ---
    bf16x8 pa[4];
#pragma unroll
    for (int mb = 0; mb < 2; ++mb) {
      float p16[16];
#pragma unroll
      for (int rr = 0; rr < 4; ++rr) {
        const float4 ejq = *(const float4*)&lds_ej[par][mb * 32 + rr * 8 + h * 4];
#pragma unroll
        for (int jl = 0; jl < 4; ++jl) {
          const int r = rr * 4 + jl;
          const float bm = __builtin_amdgcn_fmed3f(ejq[jl] - eiv, 0.f, 14.4269504f);
          const float p = exp2v(__builtin_fmaf(st[mb][r], c1, -bm));
          p16[r] = p;
          psum += p;
        }
      }
#pragma unroll
      for (int ks2 = 0; ks2 < 2; ++ks2) {
        unsigned u0 = cvtpk(p16[ks2 * 8 + 0], p16[ks2 * 8 + 1]);
        unsigned u1 = cvtpk(p16[ks2 * 8 + 2], p16[ks2 * 8 + 3]);
        unsigned v0 = cvtpk(p16[ks2 * 8 + 4], p16[ks2 * 8 + 5]);
        unsigned v1 = cvtpk(p16[ks2 * 8 + 6], p16[ks2 * 8 + 7]);
        asm volatile("v_permlane32_swap_b32 %0, %1" : "+v"(u0), "+v"(v0));
        asm volatile("v_permlane32_swap_b32 %0, %1" : "+v"(u1), "+v"(v1));
        uint4 fr; fr.x = u0; fr.y = u1; fr.z = v0; fr.w = v1;
        pa[mb * 2 + ks2] = __builtin_bit_cast(bf16x8, fr);
      }
    }

    // --- O += P @ V ---
    __builtin_amdgcn_s_setprio(1);
#pragma unroll
    for (int ks = 0; ks < 4; ++ks) {
      const int col = ks * 16 + h * 8;
#pragma unroll
      for (int nb = 0; nb < 2; ++nb) {
        const int row = nb * 32 + l31;
        bf16x8 vf = *(const bf16x8*)&lds_vt[par][row * 64 + (col ^ sw8(row))];
        o[nb] = __builtin_amdgcn_mfma_f32_32x32x16_bf16(pa[ks], vf, o[nb], 0, 0, 0);
      }
    }
    __builtin_amdgcn_s_setprio(0);

    __syncthreads();               // pair done reading vt/ej; K gloads drained
    if (more) {                    // late-write V (T14)
#pragma unroll
      for (int i = 0; i < 4; ++i) {
        union { uint4 u; unsigned short s[8]; } vu; vu.u = rv[i];
#pragma unroll
        for (int j = 0; j < 8; ++j) {
          const int d = vh + i * 8 + j;
          lds_vt[par][d * 64 + (vr ^ sw8(d))] = vu.s[j];
        }
      }
      if (wq == 0) lds_ej[par][l] = evn * cE;
    }
    __syncthreads();
  }

  // --- combine parity halves (pure sums) + epilogue ---
  psum += __shfl_xor(psum, 32, 64);        // fold h halves (same q col)
  float* xO = (float*)lds_vt;              // 4096 f32 = both vt buffers
  float* xP = (float*)lds_ej;
  if (par == 1) {
#pragma unroll
    for (int nb = 0; nb < 2; ++nb)
#pragma unroll
      for (int rr = 0; rr < 4; ++rr)
#pragma unroll
        for (int jl = 0; jl < 4; ++jl) {
          const int ql = rr * 8 + h * 4 + jl;
          xO[wq * 2048 + ql * 64 + nb * 32 + l31] = o[nb][rr * 4 + jl];
        }
    if (h == 0) xP[wq * 32 + l31] = psum;
  }
  __syncthreads();
  if (par == 0) {
    psum += xP[wq * 32 + l31];
    if (h == 0) lds_linv[wq][l31] = 1.0f / psum;
#pragma unroll
    for (int nb = 0; nb < 2; ++nb)
#pragma unroll
      for (int rr = 0; rr < 4; ++rr)
#pragma unroll
        for (int jl = 0; jl < 4; ++jl) {
          const int ql = rr * 8 + h * 4 + jl;
          o[nb][rr * 4 + jl] += xO[wq * 2048 + ql * 64 + nb * 32 + l31];
        }
  }
  __syncthreads();
  if (par == 0) {
#pragma unroll
    for (int nb = 0; nb < 2; ++nb) {
      const int col = hd * 64 + nb * 32 + l31;
#pragma unroll
      for (int rr = 0; rr < 4; ++rr) {
        const float4 lq = *(const float4*)&lds_linv[wq][rr * 8 + h * 4];
#pragma unroll
        for (int jl = 0; jl < 4; ++jl) {
          const int q = qw + rr * 8 + h * 4 + jl;
          aout[((size_t)b * 2048 + q) * 768 + col] = f2bf(o[nb][rr * 4 + jl] * lq[jl]);
        }
      }
    }
  }
}

extern "C" void kernel_launch(void* const* d_in, const int* in_sizes, int n_in,
                              void* d_out, int out_size, void* d_ws, size_t ws_size,
                              hipStream_t stream) {
  const float* x      = (const float*)d_in[0];   // [2,2048,768]
  const float* elev   = (const float*)d_in[1];   // [2,2048]
  const float* w_qkv  = (const float*)d_in[2];   // [2304,768]
  const float* w_proj = (const float*)d_in[3];   // [768,768]
  const float* b_proj = (const float*)d_in[4];   // [768]
  const float* alpha  = (const float*)d_in[5];   // [1]
  float* out = (float*)d_out;                    // [2,2048,768] f32

  unsigned short* qkvb   = (unsigned short*)d_ws;
  unsigned short* xb     = qkvb + (size_t)4096 * 2304;
  unsigned short* aob    = xb;                          // reuse after gemm1
  unsigned short* wqkvb  = xb + (size_t)4096 * 768;
  unsigned short* wprojb = wqkvb;                       // reuse after gemm1

  cvt_kernel<<<(4096 * 768 / 8 + 255) / 256, 256, 0, stream>>>(x, xb, 4096 * 768 / 8);
  cvt_kernel<<<(2304 * 768 / 8 + 255) / 256, 256, 0, stream>>>(w_qkv, wqkvb, 2304 * 768 / 8);

  gemm_bt_bf16<false><<<dim3(32, 18), 256, 0, stream>>>(
      xb, wqkvb, nullptr, qkvb, 4096, 2304, 768);

  cvt_kernel<<<(768 * 768 / 8 + 255) / 256, 256, 0, stream>>>(w_proj, wprojb, 768 * 768 / 8);

  attn_kernel<<<dim3(24, 32), 256, 0, stream>>>(qkvb, elev, alpha, aob);

  gemm_bt_bf16<true><<<dim3(32, 6), 256, 0, stream>>>(
      aob, wprojb, b_proj, out, 4096, 768, 768);
}